// Round 13
// baseline (167.062 us; speedup 1.0000x reference)
//
#include <hip/hip_runtime.h>
#include <math.h>

#define N_NODES 100000
#define N_EDGES 1600000
#define DIM 64

#define RPB   128                // rows per bucket = one node-block
#define NBUCK 782                // ceil(100000/128)
#define BCAP  2432               // mean 2048 + 8 sigma
#define TILE  2000               // edges per binA block; 800 * 2000 = E exact
#define ABLK  800                // binA grid
#define CPAD  16                 // bcnt padded: one counter per 64B line

// sigmoid(s*w+b) = rcp(1 + exp2(s*(-w*log2e) + (-b*log2e)))
__device__ __forceinline__ float fast_gate(float s, float wl, float bl2) {
    return __builtin_amdgcn_rcpf(1.0f + __builtin_amdgcn_exp2f(fmaf(s, wl, bl2)));
}

// ---------------------------------------------------------------------------
// 1) binA: bucket edges by row>>7 into per-bucket regions of bedge[].
//    800 blocks x 2000 edges (R12: was 200x8000 -> 78% of CUs idle, 22us).
//    Rows+buckets staged in LDS in pass 1; pass 2 reads only cols from
//    global. One padded global atomic per (block,bucket) reserves a run;
//    packed {lrow:7, col:17} stores land in block-exclusive runs.
// ---------------------------------------------------------------------------
__global__ __launch_bounds__(256) void binA_kernel(
    const int* __restrict__ edge, int* __restrict__ bcnt,
    int* __restrict__ bedge)
{
    __shared__ int hist[NBUCK];
    __shared__ int gbase[NBUCK];
    __shared__ int cur[NBUCK];
    __shared__ short srow[TILE];          // local row (7b) per staged edge
    __shared__ short sbkt[TILE];          // bucket id per staged edge

    const int t  = threadIdx.x;
    const int e0 = blockIdx.x * TILE;

    for (int i = t; i < NBUCK; i += 256) { hist[i] = 0; cur[i] = 0; }
    __syncthreads();

    // pass 1: stage rows, bucket histogram
    for (int i = t; i < TILE; i += 256) {
        int r = edge[e0 + i];
        int b = r >> 7;
        srow[i] = (short)(r & 127);
        sbkt[i] = (short)b;
        atomicAdd(&hist[b], 1);
    }
    __syncthreads();

    // reserve one run per non-empty bucket (padded global counters)
    for (int i = t; i < NBUCK; i += 256) {
        int h = hist[i];
        gbase[i] = (h > 0) ? (i * BCAP + atomicAdd(&bcnt[(size_t)i * CPAD], h)) : 0;
    }
    __syncthreads();

    // pass 2: place packed edges into reserved runs (cols from global once)
    for (int i = t; i < TILE; i += 256) {
        int c = edge[N_EDGES + e0 + i];
        int b = sbkt[i];
        int lrank = atomicAdd(&cur[b], 1);
        int dst = gbase[b] + lrank;
        if (dst < (b + 1) * BCAP)                 // 8-sigma guard, unreachable
            bedge[dst] = ((int)srow[i] << 17) | c;
    }
}

// ---------------------------------------------------------------------------
// 2) Fused binC + node kernel. Block = bucket (128 rows, 4 waves x 32 nodes).
//    Stage 1: read the bucket's packed edges once (coalesced), LDS
//    row-histogram + scan + in-LDS counting sort -> sedge[] by local row.
//    Stage 2 (proven gather config; pinned at ~1.9TB/s beyond-L2 across
//    7 configs — the L3 random-line ceiling): per node, Phase A lane=edge
//    -> {col,|curv diff|} into ecd; Phase B float4 x-gather + gates+fmas;
//    shfl_xor(16|32) reduce; LDS float4 Linear; exact GELU.
// ---------------------------------------------------------------------------
__global__ __launch_bounds__(256) void node_kernel(
    const float* __restrict__ x,    const float* __restrict__ curv,
    const int*   __restrict__ bcnt, const int* __restrict__ bedge,
    const float* __restrict__ Wc,   const float* __restrict__ bc,
    const float* __restrict__ Wl,   const float* __restrict__ bl,
    float* __restrict__ out)
{
    __shared__ float Ws[64][65];
    __shared__ float msl[4][64];
    __shared__ int2  ecd[4][64];
    __shared__ int   sedge[BCAP];
    __shared__ int   lhist[RPB];
    __shared__ int   lscan[RPB];
    __shared__ int   loff[RPB];
    __shared__ int   lcur[RPB];

    const int t = threadIdx.x;
    const int b = blockIdx.x;

    #pragma unroll
    for (int i = t; i < DIM * DIM; i += 256)
        Ws[i >> 6][i & 63] = Wl[i];
    if (t < RPB) { lhist[t] = 0; lcur[t] = 0; }
    __syncthreads();

    const int nb  = min(bcnt[(size_t)b * CPAD], BCAP);
    const int src = b * BCAP;

    // ---- Stage 1: in-LDS counting sort of the bucket's edges ----
    for (int j = t; j < nb; j += 256)
        atomicAdd(&lhist[bedge[src + j] >> 17], 1);
    __syncthreads();

    if (t < RPB) lscan[t] = lhist[t];
    __syncthreads();
    for (int o = 1; o < RPB; o <<= 1) {
        int u = 0;
        if (t < RPB && t >= o) u = lscan[t - o];
        __syncthreads();
        if (t < RPB) lscan[t] += u;
        __syncthreads();
    }
    if (t < RPB) loff[t] = lscan[t] - lhist[t];
    __syncthreads();

    for (int j = t; j < nb; j += 256) {
        int pv = bedge[src + j];
        int lr = pv >> 17;
        int rk = atomicAdd(&lcur[lr], 1);
        sedge[loff[lr] + rk] = pv & 0x1FFFF;
    }
    __syncthreads();

    // ---- Stage 2: gather + gate + mean + Linear + GELU ----
    const int sub  = t >> 6;            // wave in block
    const int lane = t & 63;
    const int eg   = lane >> 4;         // edge group 0..3
    const int fg   = (lane & 15) << 2;  // feature quad base
    const int d    = lane;              // output feature for Linear

    const float L2E = 1.44269504088896340736f;
    const float4 wc4 = *(const float4*)&Wc[fg];
    const float4 bc4 = *(const float4*)&bc[fg];
    const float wl0 = -wc4.x * L2E, wl1 = -wc4.y * L2E,
                wl2 = -wc4.z * L2E, wl3 = -wc4.w * L2E;
    const float bq0 = -bc4.x * L2E, bq1 = -bc4.y * L2E,
                bq2 = -bc4.z * L2E, bq3 = -bc4.w * L2E;
    const float bld = bl[d];

    for (int i = 0; i < 32; ++i) {
        const int lr   = sub * 32 + i;
        const int node = b * RPB + lr;
        if (node >= N_NODES) break;       // bucket 781 tail (wave-uniform)

        const int   start = loff[lr];
        const int   deg   = lhist[lr];
        const float cn    = curv[node];

        float a0 = 0.f, a1 = 0.f, a2 = 0.f, a3 = 0.f;

        for (int kb = 0; kb < deg; kb += 64) {
            const int pn = min(64, deg - kb);
            // Phase A: one lane per edge (cols from LDS)
            if (lane < pn) {
                int   c  = sedge[start + kb + lane];
                float cd = fabsf(cn - curv[c]);
                ecd[sub][lane] = make_int2(c, __float_as_int(cd));
            }
            // Phase B: group eg handles edges k = eg, eg+4, ... < pn
            int k = eg;
            for (; k + 4 < pn; k += 8) {
                int2 p0 = ecd[sub][k];
                int2 p1 = ecd[sub][k + 4];
                float s0 = __int_as_float(p0.y);
                float s1 = __int_as_float(p1.y);
                float4 x0 = *(const float4*)&x[((unsigned)p0.x << 6) + fg];
                float4 x1 = *(const float4*)&x[((unsigned)p1.x << 6) + fg];
                a0 = fmaf(x0.x, fast_gate(s0, wl0, bq0), a0);
                a1 = fmaf(x0.y, fast_gate(s0, wl1, bq1), a1);
                a2 = fmaf(x0.z, fast_gate(s0, wl2, bq2), a2);
                a3 = fmaf(x0.w, fast_gate(s0, wl3, bq3), a3);
                a0 = fmaf(x1.x, fast_gate(s1, wl0, bq0), a0);
                a1 = fmaf(x1.y, fast_gate(s1, wl1, bq1), a1);
                a2 = fmaf(x1.z, fast_gate(s1, wl2, bq2), a2);
                a3 = fmaf(x1.w, fast_gate(s1, wl3, bq3), a3);
            }
            if (k < pn) {
                int2 p0 = ecd[sub][k];
                float s0 = __int_as_float(p0.y);
                float4 x0 = *(const float4*)&x[((unsigned)p0.x << 6) + fg];
                a0 = fmaf(x0.x, fast_gate(s0, wl0, bq0), a0);
                a1 = fmaf(x0.y, fast_gate(s0, wl1, bq1), a1);
                a2 = fmaf(x0.z, fast_gate(s0, wl2, bq2), a2);
                a3 = fmaf(x0.w, fast_gate(s0, wl3, bq3), a3);
            }
        }

        // sum the 4 edge groups
        a0 += __shfl_xor(a0, 16); a0 += __shfl_xor(a0, 32);
        a1 += __shfl_xor(a1, 16); a1 += __shfl_xor(a1, 32);
        a2 += __shfl_xor(a2, 16); a2 += __shfl_xor(a2, 32);
        a3 += __shfl_xor(a3, 16); a3 += __shfl_xor(a3, 32);

        const float inv = __builtin_amdgcn_rcpf(fmaxf((float)deg, 1.0f));
        if (eg == 0)
            *(float4*)&msl[sub][fg] = make_float4(a0 * inv, a1 * inv, a2 * inv, a3 * inv);

        // Linear + GELU (wave-local; compiler inserts lgkmcnt waits)
        float r = bld;
        #pragma unroll
        for (int q = 0; q < DIM; q += 4) {
            float4 mv = *(const float4*)&msl[sub][q];
            float4 wv = *(const float4*)&Ws[d][q];
            r = fmaf(mv.x, wv.x, r);
            r = fmaf(mv.y, wv.y, r);
            r = fmaf(mv.z, wv.z, r);
            r = fmaf(mv.w, wv.w, r);
        }
        out[(size_t)node * DIM + d] = 0.5f * r * (1.0f + erff(r * 0.70710678118654752f));
    }
}

// ---------------------------------------------------------------------------
extern "C" void kernel_launch(void* const* d_in, const int* in_sizes, int n_in,
                              void* d_out, int out_size, void* d_ws, size_t ws_size,
                              hipStream_t stream) {
    const float* x    = (const float*)d_in[0];
    const float* curv = (const float*)d_in[1];
    const float* Wc   = (const float*)d_in[2];
    const float* bc   = (const float*)d_in[3];
    const float* Wl   = (const float*)d_in[4];
    const float* bl   = (const float*)d_in[5];
    const int*   edge = (const int*)d_in[6];

    float* out = (float*)d_out;

    // Workspace layout (~7.7 MB)
    int* bcnt  = (int*)d_ws;                         // NBUCK*CPAD (50 KB)
    int* bedge = bcnt + NBUCK * CPAD;                // NBUCK*BCAP (7.6 MB)

    hipMemsetAsync(bcnt, 0, (size_t)NBUCK * CPAD * sizeof(int), stream);

    binA_kernel<<<ABLK, 256, 0, stream>>>(edge, bcnt, bedge);
    node_kernel<<<NBUCK, 256, 0, stream>>>(
        x, curv, bcnt, bedge, Wc, bc, Wl, bl, out);
}

// Round 14
// 130.511 us; speedup vs baseline: 1.2801x; 1.2801x over previous
//
#include <hip/hip_runtime.h>
#include <math.h>

#define N_NODES 100000
#define N_EDGES 1600000
#define DIM 64

#define RPB   128                // rows per bucket = one node-block
#define NBUCK 782                // ceil(100000/128)
#define BCAP  2432               // mean 2048 + 8 sigma
#define TILE  8000               // edges per binA block; 200 * 8000 = E exact
#define ABLK  200                // binA grid (long runs: ~10 edges/run)
#define ABS   1024               // binA block size (R13: parallelism inside
                                 // the block; run structure unchanged)
#define CPAD  16                 // bcnt padded: one counter per 64B line

// sigmoid(s*w+b) = rcp(1 + exp2(s*(-w*log2e) + (-b*log2e)))
__device__ __forceinline__ float fast_gate(float s, float wl, float bl2) {
    return __builtin_amdgcn_rcpf(1.0f + __builtin_amdgcn_exp2f(fmaf(s, wl, bl2)));
}

// ---------------------------------------------------------------------------
// 1) binA: bucket edges by row>>7 into per-bucket regions of bedge[].
//    200 blocks x 8000 edges x 1024 threads. Long per-(block,bucket) runs
//    (mean 10.2 edges) keep stores L2-merged (R12 lesson: short runs =
//    full-line writebacks, +24us). Rows staged in LDS in pass 1; pass 2
//    reads only cols from global.
// ---------------------------------------------------------------------------
__global__ __launch_bounds__(ABS) void binA_kernel(
    const int* __restrict__ edge, int* __restrict__ bcnt,
    int* __restrict__ bedge)
{
    __shared__ int hist[NBUCK];
    __shared__ int gbase[NBUCK];
    __shared__ int cur[NBUCK];
    __shared__ short srow[TILE];          // local row (7b) per staged edge
    __shared__ short sbkt[TILE];          // bucket id per staged edge

    const int t  = threadIdx.x;
    const int e0 = blockIdx.x * TILE;

    for (int i = t; i < NBUCK; i += ABS) { hist[i] = 0; cur[i] = 0; }
    __syncthreads();

    // pass 1: stage rows, bucket histogram
    for (int i = t; i < TILE; i += ABS) {
        int r = edge[e0 + i];
        int b = r >> 7;
        srow[i] = (short)(r & 127);
        sbkt[i] = (short)b;
        atomicAdd(&hist[b], 1);
    }
    __syncthreads();

    // reserve one run per non-empty bucket (padded global counters)
    for (int i = t; i < NBUCK; i += ABS) {
        int h = hist[i];
        gbase[i] = (h > 0) ? (i * BCAP + atomicAdd(&bcnt[(size_t)i * CPAD], h)) : 0;
    }
    __syncthreads();

    // pass 2: place packed edges into reserved runs (cols from global once)
    for (int i = t; i < TILE; i += ABS) {
        int c = edge[N_EDGES + e0 + i];
        int b = sbkt[i];
        int lrank = atomicAdd(&cur[b], 1);
        int dst = gbase[b] + lrank;
        if (dst < (b + 1) * BCAP)                 // 8-sigma guard, unreachable
            bedge[dst] = ((int)srow[i] << 17) | c;
    }
}

// ---------------------------------------------------------------------------
// 2) Fused binC + node kernel. Block = bucket (128 rows, 4 waves x 32 nodes).
//    Stage 1: read the bucket's packed edges once (coalesced), LDS
//    row-histogram + scan + in-LDS counting sort -> sedge[] by local row.
//    Stage 2 (proven gather config; pinned at ~1.9TB/s beyond-L2 across
//    8 configs — the L3 random-line ceiling): per node, Phase A lane=edge
//    -> {col,|curv diff|} into ecd; Phase B float4 x-gather + gates+fmas;
//    shfl_xor(16|32) reduce; LDS float4 Linear; exact GELU.
// ---------------------------------------------------------------------------
__global__ __launch_bounds__(256) void node_kernel(
    const float* __restrict__ x,    const float* __restrict__ curv,
    const int*   __restrict__ bcnt, const int* __restrict__ bedge,
    const float* __restrict__ Wc,   const float* __restrict__ bc,
    const float* __restrict__ Wl,   const float* __restrict__ bl,
    float* __restrict__ out)
{
    __shared__ float Ws[64][65];
    __shared__ float msl[4][64];
    __shared__ int2  ecd[4][64];
    __shared__ int   sedge[BCAP];
    __shared__ int   lhist[RPB];
    __shared__ int   lscan[RPB];
    __shared__ int   loff[RPB];
    __shared__ int   lcur[RPB];

    const int t = threadIdx.x;
    const int b = blockIdx.x;

    #pragma unroll
    for (int i = t; i < DIM * DIM; i += 256)
        Ws[i >> 6][i & 63] = Wl[i];
    if (t < RPB) { lhist[t] = 0; lcur[t] = 0; }
    __syncthreads();

    const int nb  = min(bcnt[(size_t)b * CPAD], BCAP);
    const int src = b * BCAP;

    // ---- Stage 1: in-LDS counting sort of the bucket's edges ----
    for (int j = t; j < nb; j += 256)
        atomicAdd(&lhist[bedge[src + j] >> 17], 1);
    __syncthreads();

    if (t < RPB) lscan[t] = lhist[t];
    __syncthreads();
    for (int o = 1; o < RPB; o <<= 1) {
        int u = 0;
        if (t < RPB && t >= o) u = lscan[t - o];
        __syncthreads();
        if (t < RPB) lscan[t] += u;
        __syncthreads();
    }
    if (t < RPB) loff[t] = lscan[t] - lhist[t];
    __syncthreads();

    for (int j = t; j < nb; j += 256) {
        int pv = bedge[src + j];
        int lr = pv >> 17;
        int rk = atomicAdd(&lcur[lr], 1);
        sedge[loff[lr] + rk] = pv & 0x1FFFF;
    }
    __syncthreads();

    // ---- Stage 2: gather + gate + mean + Linear + GELU ----
    const int sub  = t >> 6;            // wave in block
    const int lane = t & 63;
    const int eg   = lane >> 4;         // edge group 0..3
    const int fg   = (lane & 15) << 2;  // feature quad base
    const int d    = lane;              // output feature for Linear

    const float L2E = 1.44269504088896340736f;
    const float4 wc4 = *(const float4*)&Wc[fg];
    const float4 bc4 = *(const float4*)&bc[fg];
    const float wl0 = -wc4.x * L2E, wl1 = -wc4.y * L2E,
                wl2 = -wc4.z * L2E, wl3 = -wc4.w * L2E;
    const float bq0 = -bc4.x * L2E, bq1 = -bc4.y * L2E,
                bq2 = -bc4.z * L2E, bq3 = -bc4.w * L2E;
    const float bld = bl[d];

    for (int i = 0; i < 32; ++i) {
        const int lr   = sub * 32 + i;
        const int node = b * RPB + lr;
        if (node >= N_NODES) break;       // bucket 781 tail (wave-uniform)

        const int   start = loff[lr];
        const int   deg   = lhist[lr];
        const float cn    = curv[node];

        float a0 = 0.f, a1 = 0.f, a2 = 0.f, a3 = 0.f;

        for (int kb = 0; kb < deg; kb += 64) {
            const int pn = min(64, deg - kb);
            // Phase A: one lane per edge (cols from LDS)
            if (lane < pn) {
                int   c  = sedge[start + kb + lane];
                float cd = fabsf(cn - curv[c]);
                ecd[sub][lane] = make_int2(c, __float_as_int(cd));
            }
            // Phase B: group eg handles edges k = eg, eg+4, ... < pn
            int k = eg;
            for (; k + 4 < pn; k += 8) {
                int2 p0 = ecd[sub][k];
                int2 p1 = ecd[sub][k + 4];
                float s0 = __int_as_float(p0.y);
                float s1 = __int_as_float(p1.y);
                float4 x0 = *(const float4*)&x[((unsigned)p0.x << 6) + fg];
                float4 x1 = *(const float4*)&x[((unsigned)p1.x << 6) + fg];
                a0 = fmaf(x0.x, fast_gate(s0, wl0, bq0), a0);
                a1 = fmaf(x0.y, fast_gate(s0, wl1, bq1), a1);
                a2 = fmaf(x0.z, fast_gate(s0, wl2, bq2), a2);
                a3 = fmaf(x0.w, fast_gate(s0, wl3, bq3), a3);
                a0 = fmaf(x1.x, fast_gate(s1, wl0, bq0), a0);
                a1 = fmaf(x1.y, fast_gate(s1, wl1, bq1), a1);
                a2 = fmaf(x1.z, fast_gate(s1, wl2, bq2), a2);
                a3 = fmaf(x1.w, fast_gate(s1, wl3, bq3), a3);
            }
            if (k < pn) {
                int2 p0 = ecd[sub][k];
                float s0 = __int_as_float(p0.y);
                float4 x0 = *(const float4*)&x[((unsigned)p0.x << 6) + fg];
                a0 = fmaf(x0.x, fast_gate(s0, wl0, bq0), a0);
                a1 = fmaf(x0.y, fast_gate(s0, wl1, bq1), a1);
                a2 = fmaf(x0.z, fast_gate(s0, wl2, bq2), a2);
                a3 = fmaf(x0.w, fast_gate(s0, wl3, bq3), a3);
            }
        }

        // sum the 4 edge groups
        a0 += __shfl_xor(a0, 16); a0 += __shfl_xor(a0, 32);
        a1 += __shfl_xor(a1, 16); a1 += __shfl_xor(a1, 32);
        a2 += __shfl_xor(a2, 16); a2 += __shfl_xor(a2, 32);
        a3 += __shfl_xor(a3, 16); a3 += __shfl_xor(a3, 32);

        const float inv = __builtin_amdgcn_rcpf(fmaxf((float)deg, 1.0f));
        if (eg == 0)
            *(float4*)&msl[sub][fg] = make_float4(a0 * inv, a1 * inv, a2 * inv, a3 * inv);

        // Linear + GELU (wave-local; compiler inserts lgkmcnt waits)
        float r = bld;
        #pragma unroll
        for (int q = 0; q < DIM; q += 4) {
            float4 mv = *(const float4*)&msl[sub][q];
            float4 wv = *(const float4*)&Ws[d][q];
            r = fmaf(mv.x, wv.x, r);
            r = fmaf(mv.y, wv.y, r);
            r = fmaf(mv.z, wv.z, r);
            r = fmaf(mv.w, wv.w, r);
        }
        out[(size_t)node * DIM + d] = 0.5f * r * (1.0f + erff(r * 0.70710678118654752f));
    }
}

// ---------------------------------------------------------------------------
extern "C" void kernel_launch(void* const* d_in, const int* in_sizes, int n_in,
                              void* d_out, int out_size, void* d_ws, size_t ws_size,
                              hipStream_t stream) {
    const float* x    = (const float*)d_in[0];
    const float* curv = (const float*)d_in[1];
    const float* Wc   = (const float*)d_in[2];
    const float* bc   = (const float*)d_in[3];
    const float* Wl   = (const float*)d_in[4];
    const float* bl   = (const float*)d_in[5];
    const int*   edge = (const int*)d_in[6];

    float* out = (float*)d_out;

    // Workspace layout (~7.7 MB)
    int* bcnt  = (int*)d_ws;                         // NBUCK*CPAD (50 KB)
    int* bedge = bcnt + NBUCK * CPAD;                // NBUCK*BCAP (7.6 MB)

    hipMemsetAsync(bcnt, 0, (size_t)NBUCK * CPAD * sizeof(int), stream);

    binA_kernel<<<ABLK, ABS, 0, stream>>>(edge, bcnt, bedge);
    node_kernel<<<NBUCK, 256, 0, stream>>>(
        x, curv, bcnt, bedge, Wc, bc, Wl, bl, out);
}